// Round 7
// baseline (3233.717 us; speedup 1.0000x reference)
//
#include <hip/hip_runtime.h>
#include <hip/hip_bf16.h>
#include <math.h>

#define BQ   512
#define EDIM 512
#define HDIM 1024
#define VDIM 1024
#define TLEN 32
#define TOUT 33
#define PLS  (BQ * VDIM)       // logits partial plane stride

typedef _Float16 half8  __attribute__((ext_vector_type(8)));
typedef _Float16 half4v __attribute__((ext_vector_type(4)));
typedef float    f32x16 __attribute__((ext_vector_type(16)));

// Packed fragment layout for an [R][K] f16 plane (K pow2):
// (r,k) -> (r>>5)*(32K) + (k>>4)*512 + ((k>>3)&1)*256 + (r&31)*8 + (k&7)
// => each (32-row strip, 16-k block) is a contiguous 1KB block; lane l owns
//    halves [l*8, l*8+8) = row (l&31), k-half (l>>5). Exactly an MFMA frag.
__device__ __forceinline__ size_t packoff(int r, int k, int K) {
    return (size_t)(r >> 5) * (size_t)(32 * K) + (size_t)(k >> 4) * 512
         + (size_t)((k >> 3) & 1) * 256 + (size_t)(r & 31) * 8 + (size_t)(k & 7);
}

// ---------------------------------------------------------------------------
// Static device buffers — write-before-read each call.
// value = hi + lo/4096 (lo pre-scaled by 2^12)
// ---------------------------------------------------------------------------
__device__ _Float16 g_curh[BQ*EDIM], g_curl[BQ*EDIM];       // packed K=512
__device__ _Float16 g_h0h[BQ*HDIM], g_h0l[BQ*HDIM];         // packed K=1024
__device__ _Float16 g_h1h[BQ*HDIM], g_h1l[BQ*HDIM];         // packed K=1024
__device__ _Float16 g_hnh[BQ*HDIM], g_hnl[BQ*HDIM];         // packed K=1024
__device__ float    g_c0[BQ*HDIM], g_c1[BQ*HDIM];

__device__ _Float16 g_wih0h[4*HDIM*EDIM], g_wih0l[4*HDIM*EDIM];  // packed K=512
__device__ _Float16 g_whh0h[4*HDIM*HDIM], g_whh0l[4*HDIM*HDIM];  // packed K=1024
__device__ _Float16 g_wih1h[4*HDIM*HDIM], g_wih1l[4*HDIM*HDIM];  // packed K=1024
__device__ _Float16 g_whh1h[4*HDIM*HDIM], g_whh1l[4*HDIM*HDIM];  // packed K=1024
__device__ _Float16 g_wouth[VDIM*HDIM],   g_woutl[VDIM*HDIM];    // packed K=1024

__device__ float g_gates[BQ * 4 * HDIM];   // gate pre-activations (bias fused)
__device__ float g_part_lg[4 * PLS];       // logits split-K partials (S=4)
__device__ float g_bsum0[4*HDIM], g_bsum1[4*HDIM];

// ---------------------------------------------------------------------------
__global__ void init_kernel(float* __restrict__ out,
                            const float* __restrict__ bi0, const float* __restrict__ bh0,
                            const float* __restrict__ bi1, const float* __restrict__ bh1) {
    int i = blockIdx.x * 256 + threadIdx.x;   // [0, BQ*HDIM)
    g_c0[i] = 0.f; g_c1[i] = 0.f;
    g_h0h[i] = (_Float16)0.f; g_h0l[i] = (_Float16)0.f;
    g_h1h[i] = (_Float16)0.f; g_h1l[i] = (_Float16)0.f;
    if (i < 4 * HDIM) {
        g_bsum0[i] = bi0[i] + bh0[i];
        g_bsum1[i] = bi1[i] + bh1[i];
    }
    if (i < 3 * BQ) {
        int which = i / BQ, b = i % BQ;
        out[(size_t)which * BQ * TOUT + (size_t)b * TOUT + (TOUT - 1)] = 0.f;
    }
}

// ---------------------------------------------------------------------------
// fp32 [R][K] -> packed (hi, lo*2^12) f16 planes. klog = log2(K).
// ---------------------------------------------------------------------------
__global__ void split_pack_kernel(const float* __restrict__ w, _Float16* __restrict__ hi,
                                  _Float16* __restrict__ lo, int klog, int nquads) {
    int q = blockIdx.x * 256 + threadIdx.x;
    if (q >= nquads) return;
    int e = q * 4;
    int r = e >> klog, k = e & ((1 << klog) - 1);
    float4 v = ((const float4*)w)[q];
    half4v h, l;
    h[0] = (_Float16)v.x; l[0] = (_Float16)((v.x - (float)h[0]) * 4096.f);
    h[1] = (_Float16)v.y; l[1] = (_Float16)((v.y - (float)h[1]) * 4096.f);
    h[2] = (_Float16)v.z; l[2] = (_Float16)((v.z - (float)h[2]) * 4096.f);
    h[3] = (_Float16)v.w; l[3] = (_Float16)((v.w - (float)h[3]) * 4096.f);
    size_t po = packoff(r, k, 1 << klog);
    *(half4v*)&hi[po] = h;
    *(half4v*)&lo[po] = l;
}

__device__ __forceinline__ void split1(float x, _Float16* hp, _Float16* lp) {
    _Float16 h = (_Float16)x;
    *hp = h;
    *lp = (_Float16)((x - (float)h) * 4096.f);
}

// ---------------------------------------------------------------------------
// Barrier-free register-pipelined MFMA GEMM. Tile 64x64, 4 waves, each wave
// owns a 32x32 quadrant (mh = w>>1, nh = w&1). All operands loaded directly
// global->VGPR from PACKED planes (contiguous 1KB frags), 4-deep register
// double-buffering (2-iter lookahead, 16 loads in flight), NO LDS, NO
// __syncthreads. Split-K over s (plane s of outp unless S==1). XCD-chunked
// block decode: blocks with equal (bid&7) share one XCD and cover a
// contiguous nb range -> weight strips are L2-resident and reused by all mb.
// nit must be a multiple of 4.
// ---------------------------------------------------------------------------
__global__ __launch_bounds__(256, 2) void gemm_nolds(
    const _Float16* __restrict__ Ah1, const _Float16* __restrict__ Al1, int K1,
    const _Float16* __restrict__ Wh1, const _Float16* __restrict__ Wl1,
    const _Float16* __restrict__ Ah2, const _Float16* __restrict__ Al2, int K2,
    const _Float16* __restrict__ Wh2, const _Float16* __restrict__ Wl2,
    const float* __restrict__ bias, float* __restrict__ outp,
    int N, int S, int P)
{
    int tid = threadIdx.x;
    int l = tid & 63, w = tid >> 6;
    int lr = l & 31, lq = l >> 5;
    int mh = w >> 1, nh = w & 1;

    int wb = blockIdx.x;
    int xcd = wb & 7, q = wb >> 3;
    int nb = xcd * P + (q % P);
    int rest = q / P;
    int s = rest % S;
    int mb = rest / S;

    int kch1 = K1 / S, kch2 = K2 / S;
    int n1 = kch1 >> 5;
    int nit = n1 + (kch2 >> 5);

    size_t aoff1 = (size_t)(mb*2+mh) * (size_t)(32*K1) + (size_t)((s*kch1) >> 4) * 512 + (size_t)l*8;
    size_t boff1 = (size_t)(nb*2+nh) * (size_t)(32*K1) + (size_t)((s*kch1) >> 4) * 512 + (size_t)l*8;
    const _Float16* pAh1 = Ah1 + aoff1;
    const _Float16* pAl1 = Al1 + aoff1;
    const _Float16* pWh1 = Wh1 + boff1;
    const _Float16* pWl1 = Wl1 + boff1;
    const _Float16 *pAh2 = pAh1, *pAl2 = pAl1, *pWh2 = pWh1, *pWl2 = pWl1;
    if (K2 > 0) {
        size_t aoff2 = (size_t)(mb*2+mh) * (size_t)(32*K2) + (size_t)((s*kch2) >> 4) * 512 + (size_t)l*8;
        size_t boff2 = (size_t)(nb*2+nh) * (size_t)(32*K2) + (size_t)((s*kch2) >> 4) * 512 + (size_t)l*8;
        pAh2 = Ah2 + aoff2; pAl2 = Al2 + aoff2;
        pWh2 = Wh2 + boff2; pWl2 = Wl2 + boff2;
    }

    f32x16 accM = {}, accL = {};

#define LOAD_IT(it, A, B) { \
        int it_ = (it); size_t off_; \
        const _Float16 *ah_, *al_, *wh_, *wl_; \
        if (it_ < n1) { off_ = (size_t)it_ * 1024;        ah_ = pAh1; al_ = pAl1; wh_ = pWh1; wl_ = pWl1; } \
        else          { off_ = (size_t)(it_ - n1) * 1024; ah_ = pAh2; al_ = pAl2; wh_ = pWh2; wl_ = pWl2; } \
        A[0][0] = *(const half8*)(ah_ + off_);       A[0][1] = *(const half8*)(ah_ + off_ + 512); \
        A[1][0] = *(const half8*)(al_ + off_);       A[1][1] = *(const half8*)(al_ + off_ + 512); \
        B[0][0] = *(const half8*)(wh_ + off_);       B[0][1] = *(const half8*)(wh_ + off_ + 512); \
        B[1][0] = *(const half8*)(wl_ + off_);       B[1][1] = *(const half8*)(wl_ + off_ + 512); \
    }

#define COMP_IT(A, B) { \
        _Pragma("unroll") \
        for (int kh_ = 0; kh_ < 2; ++kh_) { \
            accM = __builtin_amdgcn_mfma_f32_32x32x16_f16(A[0][kh_], B[0][kh_], accM, 0, 0, 0); \
            accL = __builtin_amdgcn_mfma_f32_32x32x16_f16(A[0][kh_], B[1][kh_], accL, 0, 0, 0); \
            accL = __builtin_amdgcn_mfma_f32_32x32x16_f16(A[1][kh_], B[0][kh_], accL, 0, 0, 0); \
        } \
    }

    half8 A0[2][2], B0[2][2], A1[2][2], B1[2][2];
    half8 A2[2][2], B2[2][2], A3[2][2], B3[2][2];
    LOAD_IT(0, A0, B0);
    LOAD_IT(1, A1, B1);
    for (int itp = 0; itp < nit; itp += 4) {      // nit % 4 == 0 (48 / 64 / 8)
        if (itp + 2 < nit) LOAD_IT(itp + 2, A2, B2);
        COMP_IT(A0, B0);
        if (itp + 3 < nit) LOAD_IT(itp + 3, A3, B3);
        COMP_IT(A1, B1);
        if (itp + 4 < nit) LOAD_IT(itp + 4, A0, B0);
        COMP_IT(A2, B2);
        if (itp + 5 < nit) LOAD_IT(itp + 5, A1, B1);
        COMP_IT(A3, B3);
    }
#undef LOAD_IT
#undef COMP_IT

    // epilogue: C/D layout n = l&31, m = (r&3)+8*(r>>2)+4*(l>>5)
    int n = nb * 64 + nh * 32 + lr;
    int m0 = mb * 64 + mh * 32;
    float bv = bias ? bias[n] : 0.f;
    float* op = outp + (size_t)s * BQ * N;
    #pragma unroll
    for (int r = 0; r < 16; ++r) {
        int row = (r & 3) + 8 * (r >> 2) + 4 * lq;
        op[(size_t)(m0 + row) * N + n] = accM[r] + accL[r] * (1.f / 4096.f) + bv;
    }
}

// ---------------------------------------------------------------------------
// fp32 GEMM for inp = x @ w_in^T + b_in (once, K=64); writes packed cur
// ---------------------------------------------------------------------------
#define GBK 16
#define GPAD 68
__global__ __launch_bounds__(256) void gemm_in(const float* __restrict__ x,
                                               const float* __restrict__ w_in,
                                               const float* __restrict__ b_in) {
    __shared__ __align__(16) float As[GBK][GPAD];
    __shared__ __align__(16) float Bs[GBK][GPAD];
    int tid = threadIdx.x;
    int tx = tid & 15, ty = tid >> 4;
    int m0 = blockIdx.y * 64, n0 = blockIdx.x * 64;
    int lm = tid >> 2, lk = (tid & 3) << 2;
    const int K = 64;
    float acc[4][4] = {};
    for (int k0 = 0; k0 < K; k0 += GBK) {
        float4 av = *(const float4*)(x + (size_t)(m0 + lm) * K + k0 + lk);
        float4 wv = *(const float4*)(w_in + (size_t)(n0 + lm) * K + k0 + lk);
        As[lk + 0][lm] = av.x; As[lk + 1][lm] = av.y;
        As[lk + 2][lm] = av.z; As[lk + 3][lm] = av.w;
        Bs[lk + 0][lm] = wv.x; Bs[lk + 1][lm] = wv.y;
        Bs[lk + 2][lm] = wv.z; Bs[lk + 3][lm] = wv.w;
        __syncthreads();
        #pragma unroll
        for (int kk = 0; kk < GBK; ++kk) {
            float4 a  = *(const float4*)&As[kk][ty * 4];
            float4 bq = *(const float4*)&Bs[kk][tx * 4];
            float aa[4] = {a.x, a.y, a.z, a.w};
            float bb[4] = {bq.x, bq.y, bq.z, bq.w};
            #pragma unroll
            for (int i = 0; i < 4; ++i)
                #pragma unroll
                for (int j = 0; j < 4; ++j)
                    acc[i][j] = fmaf(aa[i], bb[j], acc[i][j]);
        }
        __syncthreads();
    }
    #pragma unroll
    for (int i = 0; i < 4; ++i) {
        int m = m0 + ty * 4 + i;
        int n = n0 + tx * 4;
        half4v h, lo;
        #pragma unroll
        for (int j = 0; j < 4; ++j) {
            float v = acc[i][j] + b_in[n + j];
            _Float16 hv = (_Float16)v;
            h[j] = hv;
            lo[j] = (_Float16)((v - (float)hv) * 4096.f);
        }
        size_t po = packoff(m, n, EDIM);
        *(half4v*)&g_curh[po] = h;
        *(half4v*)&g_curl[po] = lo;
    }
}

__device__ __forceinline__ float sigm(float x) { return 1.f / (1.f + expf(-x)); }

// ---------------------------------------------------------------------------
// LSTM cell 0: gates (bias fused) -> h0 (packed K=1024), c0.
// ---------------------------------------------------------------------------
__global__ void lstm0_kernel() {
    int qidx = blockIdx.x * 256 + threadIdx.x;
    int b = qidx >> 8;
    int j = (qidx & 255) * 4;
    size_t base = (size_t)b * 4096;
    float4 G[4];
    #pragma unroll
    for (int g = 0; g < 4; ++g) G[g] = *(const float4*)&g_gates[base + g * 1024 + j];
    size_t hb = (size_t)b * HDIM + j;
    float4 cin = *(const float4*)&g_c0[hb];
    float ci[4] = {cin.x, cin.y, cin.z, cin.w};
    float gi[4] = {G[0].x, G[0].y, G[0].z, G[0].w};
    float gf[4] = {G[1].x, G[1].y, G[1].z, G[1].w};
    float gg[4] = {G[2].x, G[2].y, G[2].z, G[2].w};
    float go[4] = {G[3].x, G[3].y, G[3].z, G[3].w};
    float c[4], h[4];
    half4v hh, hl;
    #pragma unroll
    for (int r = 0; r < 4; ++r) {
        c[r] = sigm(gf[r]) * ci[r] + sigm(gi[r]) * tanhf(gg[r]);
        h[r] = sigm(go[r]) * tanhf(c[r]);
        _Float16 hi16 = (_Float16)h[r];
        hh[r] = hi16;
        hl[r] = (_Float16)((h[r] - (float)hi16) * 4096.f);
    }
    *(float4*)&g_c0[hb] = {c[0], c[1], c[2], c[3]};
    size_t po = packoff(b, j, HDIM);
    *(half4v*)&g_h0h[po] = hh;
    *(half4v*)&g_h0l[po] = hl;
}

// ---------------------------------------------------------------------------
// LSTM cell 1 + LayerNorm: one block per row; writes packed h1, hn.
// ---------------------------------------------------------------------------
__global__ __launch_bounds__(256) void lstm1_ln_kernel(
    const float* __restrict__ ln_g, const float* __restrict__ ln_b)
{
    __shared__ float sbuf[4];
    int b = blockIdx.x, tid = threadIdx.x;
    int lane = tid & 63, wid = tid >> 6;
    int j = tid * 4;
    size_t base = (size_t)b * 4096;
    float4 G[4];
    #pragma unroll
    for (int g = 0; g < 4; ++g) G[g] = *(const float4*)&g_gates[base + g * 1024 + j];
    size_t hb = (size_t)b * HDIM + j;
    float4 cin = *(const float4*)&g_c1[hb];
    float ci[4] = {cin.x, cin.y, cin.z, cin.w};
    float gi[4] = {G[0].x, G[0].y, G[0].z, G[0].w};
    float gf[4] = {G[1].x, G[1].y, G[1].z, G[1].w};
    float gg[4] = {G[2].x, G[2].y, G[2].z, G[2].w};
    float go[4] = {G[3].x, G[3].y, G[3].z, G[3].w};
    float c[4], h[4];
    float sum = 0.f;
    #pragma unroll
    for (int r = 0; r < 4; ++r) {
        c[r] = sigm(gf[r]) * ci[r] + sigm(gi[r]) * tanhf(gg[r]);
        h[r] = sigm(go[r]) * tanhf(c[r]);
        sum += h[r];
    }
    *(float4*)&g_c1[hb] = {c[0], c[1], c[2], c[3]};
    size_t po = packoff(b, j, HDIM);
    half4v h1h, h1l;
    #pragma unroll
    for (int r = 0; r < 4; ++r) {
        _Float16 hi16 = (_Float16)h[r];
        h1h[r] = hi16;
        h1l[r] = (_Float16)((h[r] - (float)hi16) * 4096.f);
    }
    *(half4v*)&g_h1h[po] = h1h;
    *(half4v*)&g_h1l[po] = h1l;

    for (int off = 32; off > 0; off >>= 1) sum += __shfl_down(sum, off, 64);
    if (lane == 0) sbuf[wid] = sum;
    __syncthreads();
    float mu = (sbuf[0] + sbuf[1] + sbuf[2] + sbuf[3]) * (1.f / HDIM);
    __syncthreads();
    float sq = 0.f;
    #pragma unroll
    for (int r = 0; r < 4; ++r) { float d = h[r] - mu; sq += d * d; }
    for (int off = 32; off > 0; off >>= 1) sq += __shfl_down(sq, off, 64);
    if (lane == 0) sbuf[wid] = sq;
    __syncthreads();
    float var = (sbuf[0] + sbuf[1] + sbuf[2] + sbuf[3]) * (1.f / HDIM);
    float rstd = 1.f / sqrtf(var + 1e-5f);
    half4v nh, nl;
    #pragma unroll
    for (int r = 0; r < 4; ++r) {
        float hn = (h[r] - mu) * rstd * ln_g[j + r] + ln_b[j + r];
        _Float16 hi16 = (_Float16)hn;
        nh[r] = hi16;
        nl[r] = (_Float16)((hn - (float)hi16) * 4096.f);
    }
    *(half4v*)&g_hnh[po] = nh;
    *(half4v*)&g_hnl[po] = nl;
}

// ---------------------------------------------------------------------------
// per-row softmax over logits = sum of 4 partials + b_out; writes packed cur
// ---------------------------------------------------------------------------
__global__ __launch_bounds__(256) void softmax_row_kernel(
    const float* __restrict__ b_out, const float* __restrict__ emb,
    float* __restrict__ out, int t)
{
    __shared__ float swv[4];
    __shared__ int   swi[4];
    __shared__ float sZ[4], sS[4];
    __shared__ float s_max;
    __shared__ int   s_idx;
    int b = blockIdx.x, tid = threadIdx.x;
    int lane = tid & 63, wid = tid >> 6;
    size_t base = (size_t)b * VDIM + 4 * tid;
    float4 xv = *(const float4*)&b_out[4 * tid];
    #pragma unroll
    for (int s = 0; s < 4; ++s) {
        float4 p = *(const float4*)&g_part_lg[(size_t)s * PLS + base];
        xv.x += p.x; xv.y += p.y; xv.z += p.z; xv.w += p.w;
    }

    float mv = xv.x; int mi = 4 * tid;
    if (xv.y > mv) { mv = xv.y; mi = 4 * tid + 1; }
    if (xv.z > mv) { mv = xv.z; mi = 4 * tid + 2; }
    if (xv.w > mv) { mv = xv.w; mi = 4 * tid + 3; }
    for (int off = 32; off > 0; off >>= 1) {
        float ov = __shfl_down(mv, off, 64);
        int   oi = __shfl_down(mi, off, 64);
        if (ov > mv || (ov == mv && oi < mi)) { mv = ov; mi = oi; }
    }
    if (lane == 0) { swv[wid] = mv; swi[wid] = mi; }
    __syncthreads();
    if (tid == 0) {
        mv = swv[0]; mi = swi[0];
        for (int w = 1; w < 4; ++w)
            if (swv[w] > mv || (swv[w] == mv && swi[w] < mi)) { mv = swv[w]; mi = swi[w]; }
        s_max = mv; s_idx = mi;
    }
    __syncthreads();
    float xmax = s_max;

    float sv[4] = {xv.x - xmax, xv.y - xmax, xv.z - xmax, xv.w - xmax};
    float z = 0.f, s1 = 0.f;
    #pragma unroll
    for (int r = 0; r < 4; ++r) { float e = expf(sv[r]); z += e; s1 += e * sv[r]; }
    for (int off = 32; off > 0; off >>= 1) {
        z  += __shfl_down(z, off, 64);
        s1 += __shfl_down(s1, off, 64);
    }
    if (lane == 0) { sZ[wid] = z; sS[wid] = s1; }
    __syncthreads();
    if (tid == 0) {
        float Z = sZ[0] + sZ[1] + sZ[2] + sZ[3];
        float S1 = sS[0] + sS[1] + sS[2] + sS[3];
        float logZ = logf(Z);
        float ent = logZ - S1 / Z;
        out[(size_t)b * TOUT + t]                         = (float)s_idx;
        out[(size_t)BQ * TOUT + (size_t)b * TOUT + t]     = -logZ;
        out[(size_t)2 * BQ * TOUT + (size_t)b * TOUT + t] = ent;
    }
    __syncthreads();
    int sym = s_idx;
    const float* e = emb + (size_t)sym * EDIM;
    for (int j = tid; j < EDIM; j += 256) {
        size_t po = packoff(b, j, EDIM);
        split1(e[j], &g_curh[po], &g_curl[po]);
    }
}

// ---------------------------------------------------------------------------
extern "C" void kernel_launch(void* const* d_in, const int* in_sizes, int n_in,
                              void* d_out, int out_size, void* d_ws, size_t ws_size,
                              hipStream_t stream) {
    const float* x     = (const float*)d_in[0];
    const float* w_in  = (const float*)d_in[1];
    const float* b_in  = (const float*)d_in[2];
    const float* w_ih0 = (const float*)d_in[3];
    const float* w_hh0 = (const float*)d_in[4];
    const float* b_ih0 = (const float*)d_in[5];
    const float* b_hh0 = (const float*)d_in[6];
    const float* w_ih1 = (const float*)d_in[7];
    const float* w_hh1 = (const float*)d_in[8];
    const float* b_ih1 = (const float*)d_in[9];
    const float* b_hh1 = (const float*)d_in[10];
    const float* ln_g  = (const float*)d_in[11];
    const float* ln_b  = (const float*)d_in[12];
    const float* w_out = (const float*)d_in[13];
    const float* b_out = (const float*)d_in[14];
    const float* emb   = (const float*)d_in[15];
    float* out = (float*)d_out;

    _Float16 *wih0h, *wih0l, *whh0h, *whh0l, *wih1h, *wih1l, *whh1h, *whh1l, *wouth, *woutl;
    hipGetSymbolAddress((void**)&wih0h, HIP_SYMBOL(g_wih0h));
    hipGetSymbolAddress((void**)&wih0l, HIP_SYMBOL(g_wih0l));
    hipGetSymbolAddress((void**)&whh0h, HIP_SYMBOL(g_whh0h));
    hipGetSymbolAddress((void**)&whh0l, HIP_SYMBOL(g_whh0l));
    hipGetSymbolAddress((void**)&wih1h, HIP_SYMBOL(g_wih1h));
    hipGetSymbolAddress((void**)&wih1l, HIP_SYMBOL(g_wih1l));
    hipGetSymbolAddress((void**)&whh1h, HIP_SYMBOL(g_whh1h));
    hipGetSymbolAddress((void**)&whh1l, HIP_SYMBOL(g_whh1l));
    hipGetSymbolAddress((void**)&wouth, HIP_SYMBOL(g_wouth));
    hipGetSymbolAddress((void**)&woutl, HIP_SYMBOL(g_woutl));
    _Float16 *curh, *curl, *h0h, *h0l, *h1h, *h1l, *hnh, *hnl;
    hipGetSymbolAddress((void**)&curh, HIP_SYMBOL(g_curh));
    hipGetSymbolAddress((void**)&curl, HIP_SYMBOL(g_curl));
    hipGetSymbolAddress((void**)&h0h, HIP_SYMBOL(g_h0h));
    hipGetSymbolAddress((void**)&h0l, HIP_SYMBOL(g_h0l));
    hipGetSymbolAddress((void**)&h1h, HIP_SYMBOL(g_h1h));
    hipGetSymbolAddress((void**)&h1l, HIP_SYMBOL(g_h1l));
    hipGetSymbolAddress((void**)&hnh, HIP_SYMBOL(g_hnh));
    hipGetSymbolAddress((void**)&hnl, HIP_SYMBOL(g_hnl));
    float *gates, *part_lg, *bsum0, *bsum1;
    hipGetSymbolAddress((void**)&gates, HIP_SYMBOL(g_gates));
    hipGetSymbolAddress((void**)&part_lg, HIP_SYMBOL(g_part_lg));
    hipGetSymbolAddress((void**)&bsum0, HIP_SYMBOL(g_bsum0));
    hipGetSymbolAddress((void**)&bsum1, HIP_SYMBOL(g_bsum1));

    init_kernel<<<(BQ * HDIM) / 256, 256, 0, stream>>>(out, b_ih0, b_hh0, b_ih1, b_hh1);

    // one-time weight split+pack (klog = log2 K)
    split_pack_kernel<<<(4*HDIM*EDIM/4 + 255)/256, 256, 0, stream>>>(w_ih0, wih0h, wih0l, 9,  4*HDIM*EDIM/4);
    split_pack_kernel<<<(4*HDIM*HDIM/4 + 255)/256, 256, 0, stream>>>(w_hh0, whh0h, whh0l, 10, 4*HDIM*HDIM/4);
    split_pack_kernel<<<(4*HDIM*HDIM/4 + 255)/256, 256, 0, stream>>>(w_ih1, wih1h, wih1l, 10, 4*HDIM*HDIM/4);
    split_pack_kernel<<<(4*HDIM*HDIM/4 + 255)/256, 256, 0, stream>>>(w_hh1, whh1h, whh1l, 10, 4*HDIM*HDIM/4);
    split_pack_kernel<<<(VDIM*HDIM/4 + 255)/256, 256, 0, stream>>>(w_out, wouth, woutl, 10, VDIM*HDIM/4);

    gemm_in<<<dim3(EDIM / 64, BQ / 64), 256, 0, stream>>>(x, w_in, b_in);

    for (int t = 0; t < TLEN; ++t) {
        // gates0 = cur @ w_ih0^T + h0 @ w_hh0^T + bsum0   (S=1 direct, P=8)
        gemm_nolds<<<512, 256, 0, stream>>>(
            curh, curl, EDIM, wih0h, wih0l,
            h0h, h0l, HDIM, whh0h, whh0l,
            bsum0, gates, 4 * HDIM, 1, 8);
        lstm0_kernel<<<(BQ * HDIM / 4) / 256, 256, 0, stream>>>();

        // gates1 = h0 @ w_ih1^T + h1 @ w_hh1^T + bsum1    (S=1 direct, P=8)
        gemm_nolds<<<512, 256, 0, stream>>>(
            h0h, h0l, HDIM, wih1h, wih1l,
            h1h, h1l, HDIM, whh1h, whh1l,
            bsum1, gates, 4 * HDIM, 1, 8);
        lstm1_ln_kernel<<<BQ, 256, 0, stream>>>(ln_g, ln_b);

        // logits partials = hn @ w_out^T   (S=4 -> 4 planes, P=2)
        gemm_nolds<<<512, 256, 0, stream>>>(
            hnh, hnl, HDIM, wouth, woutl,
            (const _Float16*)nullptr, (const _Float16*)nullptr, 0,
            (const _Float16*)nullptr, (const _Float16*)nullptr,
            (const float*)nullptr, part_lg, VDIM, 4, 2);

        softmax_row_kernel<<<BQ, 256, 0, stream>>>(b_out, emb, out, t);
    }
}

// Round 8
// 3126.567 us; speedup vs baseline: 1.0343x; 1.0343x over previous
//
#include <hip/hip_runtime.h>
#include <hip/hip_bf16.h>
#include <math.h>

#define BQ   512
#define EDIM 512
#define HDIM 1024
#define VDIM 1024
#define TLEN 32
#define TOUT 33
#define PLS  (BQ * VDIM)       // logits partial plane stride

typedef _Float16 half8  __attribute__((ext_vector_type(8)));
typedef _Float16 half4v __attribute__((ext_vector_type(4)));
typedef float    f32x16 __attribute__((ext_vector_type(16)));

#define GLOAD_LDS16(gp, lp) __builtin_amdgcn_global_load_lds( \
    (const __attribute__((address_space(1))) void*)(gp),      \
    (__attribute__((address_space(3))) void*)(lp), 16, 0, 0)

// Packed fragment layout for an [R][K] f16 plane (K pow2):
// (r,k) -> (r>>5)*(32K) + (k>>4)*512 + ((k>>3)&1)*256 + (r&31)*8 + (k&7)
// => each (32-row strip, 16-k block) is a contiguous 1KB block; lane l owns
//    halves [l*8, l*8+8) = row (l&31), k-half (l>>5). Exactly an MFMA frag.
__device__ __forceinline__ size_t packoff(int r, int k, int K) {
    return (size_t)(r >> 5) * (size_t)(32 * K) + (size_t)(k >> 4) * 512
         + (size_t)((k >> 3) & 1) * 256 + (size_t)(r & 31) * 8 + (size_t)(k & 7);
}

// ---------------------------------------------------------------------------
// Static device buffers — write-before-read each call.
// value = hi + lo/4096 (lo pre-scaled by 2^12)
// ---------------------------------------------------------------------------
__device__ _Float16 g_curh[BQ*EDIM], g_curl[BQ*EDIM];       // packed K=512
__device__ _Float16 g_h0h[BQ*HDIM], g_h0l[BQ*HDIM];         // packed K=1024
__device__ _Float16 g_h1h[BQ*HDIM], g_h1l[BQ*HDIM];         // packed K=1024
__device__ _Float16 g_hnh[BQ*HDIM], g_hnl[BQ*HDIM];         // packed K=1024
__device__ float    g_c0[BQ*HDIM], g_c1[BQ*HDIM];

__device__ _Float16 g_wih0h[4*HDIM*EDIM], g_wih0l[4*HDIM*EDIM];  // packed K=512
__device__ _Float16 g_whh0h[4*HDIM*HDIM], g_whh0l[4*HDIM*HDIM];  // packed K=1024
__device__ _Float16 g_wih1h[4*HDIM*HDIM], g_wih1l[4*HDIM*HDIM];  // packed K=1024
__device__ _Float16 g_whh1h[4*HDIM*HDIM], g_whh1l[4*HDIM*HDIM];  // packed K=1024
__device__ _Float16 g_wouth[VDIM*HDIM],   g_woutl[VDIM*HDIM];    // packed K=1024

__device__ float g_gates[BQ * 4 * HDIM];   // gate pre-activations (bias fused)
__device__ float g_part_lg[4 * PLS];       // logits split-K partials (S=4)
__device__ float g_bsum0[4*HDIM], g_bsum1[4*HDIM];

// ---------------------------------------------------------------------------
__global__ void init_kernel(float* __restrict__ out,
                            const float* __restrict__ bi0, const float* __restrict__ bh0,
                            const float* __restrict__ bi1, const float* __restrict__ bh1) {
    int i = blockIdx.x * 256 + threadIdx.x;   // [0, BQ*HDIM)
    g_c0[i] = 0.f; g_c1[i] = 0.f;
    g_h0h[i] = (_Float16)0.f; g_h0l[i] = (_Float16)0.f;
    g_h1h[i] = (_Float16)0.f; g_h1l[i] = (_Float16)0.f;
    if (i < 4 * HDIM) {
        g_bsum0[i] = bi0[i] + bh0[i];
        g_bsum1[i] = bi1[i] + bh1[i];
    }
    if (i < 3 * BQ) {
        int which = i / BQ, b = i % BQ;
        out[(size_t)which * BQ * TOUT + (size_t)b * TOUT + (TOUT - 1)] = 0.f;
    }
}

// ---------------------------------------------------------------------------
// fp32 [R][K] -> packed (hi, lo*2^12) f16 planes. klog = log2(K).
// ---------------------------------------------------------------------------
__global__ void split_pack_kernel(const float* __restrict__ w, _Float16* __restrict__ hi,
                                  _Float16* __restrict__ lo, int klog, int nquads) {
    int q = blockIdx.x * 256 + threadIdx.x;
    if (q >= nquads) return;
    int e = q * 4;
    int r = e >> klog, k = e & ((1 << klog) - 1);
    float4 v = ((const float4*)w)[q];
    half4v h, l;
    h[0] = (_Float16)v.x; l[0] = (_Float16)((v.x - (float)h[0]) * 4096.f);
    h[1] = (_Float16)v.y; l[1] = (_Float16)((v.y - (float)h[1]) * 4096.f);
    h[2] = (_Float16)v.z; l[2] = (_Float16)((v.z - (float)h[2]) * 4096.f);
    h[3] = (_Float16)v.w; l[3] = (_Float16)((v.w - (float)h[3]) * 4096.f);
    size_t po = packoff(r, k, 1 << klog);
    *(half4v*)&hi[po] = h;
    *(half4v*)&lo[po] = l;
}

__device__ __forceinline__ void split1(float x, _Float16* hp, _Float16* lp) {
    _Float16 h = (_Float16)x;
    *hp = h;
    *lp = (_Float16)((x - (float)h) * 4096.f);
}

// ---------------------------------------------------------------------------
// Pipelined MFMA GEMM. Tile 64(M)x128(N), 4 waves; wave w owns n-strip w*32
// and computes 64x32 (2 m-frags). A (hi+lo) -> LDS via global_load_lds from
// packed planes, 4-buffer rotation, staged 2 iters ahead; wave w stages the
// (pl=w>>1, mh=w&1) frag pair. B (hi+lo) -> VGPR, 4 named slots, 2 ahead.
// Sync: counted s_waitcnt vmcnt(12) + raw s_barrier (never vmcnt(0) in loop).
// Per iter fixed 6 VMEM/wave: 2 gload_lds + 4 B loads. nit % 4 == 0, nit >= 4.
// XCD-slab decode: xcd = bid&7 owns n-tiles [xcd*NTP, (xcd+1)*NTP).
// ---------------------------------------------------------------------------
__global__ __launch_bounds__(256) void gemm_pipe(
    const _Float16* __restrict__ Ah1, const _Float16* __restrict__ Al1, int K1,
    const _Float16* __restrict__ Wh1, const _Float16* __restrict__ Wl1,
    const _Float16* __restrict__ Ah2, const _Float16* __restrict__ Al2, int K2,
    const _Float16* __restrict__ Wh2, const _Float16* __restrict__ Wl2,
    const float* __restrict__ bias, float* __restrict__ outp,
    int N, int S, int NTP)
{
    __shared__ __align__(16) _Float16 sA[4][2][2][2][512]; // [buf][pl][mh][kh] 32KB
    int tid = threadIdx.x;
    int l = tid & 63, w = tid >> 6;
    int lr = l & 31, lq = l >> 5;
    int plw = w >> 1, mhw = w & 1;

    int wb = blockIdx.x;
    int xcd = wb & 7, q = wb >> 3;
    int nt = xcd * NTP + q % NTP;     // n-tile (128 wide)
    int rest = q / NTP;
    int s = rest % S;
    int mb = rest / S;                 // m-tile (64 rows)

    int kch1 = K1 / S, kch2 = (K2 > 0) ? (K2 / S) : 0;
    int n1 = kch1 >> 5;
    int nit = n1 + (kch2 >> 5);

    // per-wave source bases (packed planes; all include lane offset l*8)
    const _Float16* pA1 = (plw ? Al1 : Ah1)
        + (size_t)(mb*2 + mhw) * (size_t)(32*K1) + (size_t)((s*kch1) >> 4) * 512 + (size_t)l*8;
    const _Float16* pWh1 = Wh1
        + (size_t)(nt*4 + w) * (size_t)(32*K1) + (size_t)((s*kch1) >> 4) * 512 + (size_t)l*8;
    const _Float16* pWl1 = Wl1
        + (size_t)(nt*4 + w) * (size_t)(32*K1) + (size_t)((s*kch1) >> 4) * 512 + (size_t)l*8;
    const _Float16 *pA2 = pA1, *pWh2 = pWh1, *pWl2 = pWl1;
    if (K2 > 0) {
        pA2 = (plw ? Al2 : Ah2)
            + (size_t)(mb*2 + mhw) * (size_t)(32*K2) + (size_t)((s*kch2) >> 4) * 512 + (size_t)l*8;
        pWh2 = Wh2
            + (size_t)(nt*4 + w) * (size_t)(32*K2) + (size_t)((s*kch2) >> 4) * 512 + (size_t)l*8;
        pWl2 = Wl2
            + (size_t)(nt*4 + w) * (size_t)(32*K2) + (size_t)((s*kch2) >> 4) * 512 + (size_t)l*8;
    }

    f32x16 accM0 = {}, accM1 = {}, accL0 = {}, accL1 = {};
    half8 B0h[2], B0l[2], B1h[2], B1l[2], B2h[2], B2l[2], B3h[2], B3l[2];

    // issue group IT (A frags -> LDS slot IT&3 conceptually handled by caller)
#define STAGE(IT, SLOT, BH, BL)                                                \
    {                                                                          \
        int it_ = (IT);                                                        \
        bool g1_ = it_ < n1;                                                   \
        const _Float16* ap_ = g1_ ? pA1 : pA2;                                 \
        const _Float16* wh_ = g1_ ? pWh1 : pWh2;                               \
        const _Float16* wl_ = g1_ ? pWl1 : pWl2;                               \
        size_t off_ = (size_t)(g1_ ? it_ : it_ - n1) * 1024;                   \
        GLOAD_LDS16(ap_ + off_,       &sA[SLOT][plw][mhw][0][0]);              \
        GLOAD_LDS16(ap_ + off_ + 512, &sA[SLOT][plw][mhw][1][0]);              \
        BH[0] = *(const half8*)(wh_ + off_);                                   \
        BH[1] = *(const half8*)(wh_ + off_ + 512);                             \
        BL[0] = *(const half8*)(wl_ + off_);                                   \
        BL[1] = *(const half8*)(wl_ + off_ + 512);                             \
    }

#define COMPUTE(BUF, BH, BL)                                                   \
    {                                                                          \
        _Pragma("unroll")                                                      \
        for (int kh_ = 0; kh_ < 2; ++kh_) {                                    \
            half8 ah0 = *(const half8*)&sA[BUF][0][0][kh_][(size_t)l * 8];     \
            half8 ah1 = *(const half8*)&sA[BUF][0][1][kh_][(size_t)l * 8];     \
            half8 al0 = *(const half8*)&sA[BUF][1][0][kh_][(size_t)l * 8];     \
            half8 al1 = *(const half8*)&sA[BUF][1][1][kh_][(size_t)l * 8];     \
            accM0 = __builtin_amdgcn_mfma_f32_32x32x16_f16(ah0, BH[kh_], accM0, 0, 0, 0); \
            accM1 = __builtin_amdgcn_mfma_f32_32x32x16_f16(ah1, BH[kh_], accM1, 0, 0, 0); \
            accL0 = __builtin_amdgcn_mfma_f32_32x32x16_f16(ah0, BL[kh_], accL0, 0, 0, 0); \
            accL1 = __builtin_amdgcn_mfma_f32_32x32x16_f16(ah1, BL[kh_], accL1, 0, 0, 0); \
            accL0 = __builtin_amdgcn_mfma_f32_32x32x16_f16(al0, BH[kh_], accL0, 0, 0, 0); \
            accL1 = __builtin_amdgcn_mfma_f32_32x32x16_f16(al1, BH[kh_], accL1, 0, 0, 0); \
        }                                                                      \
    }

// counted wait: 2 groups of 6 VMEM in flight while group IT completes
#define WAITSYNC(IT)                                                           \
    {                                                                          \
        if ((IT) < nit - 2)      asm volatile("s_waitcnt vmcnt(12)" ::: "memory"); \
        else if ((IT) == nit - 2) asm volatile("s_waitcnt vmcnt(6)"  ::: "memory"); \
        else                      asm volatile("s_waitcnt vmcnt(0)"  ::: "memory"); \
        __builtin_amdgcn_sched_barrier(0);                                     \
        __builtin_amdgcn_s_barrier();                                          \
    }

#define ITER(IT, BUF, BHc, BLc, BHn, BLn)                                      \
    {                                                                          \
        if ((IT) + 2 < nit) STAGE((IT) + 2, ((BUF) + 2) & 3, BHn, BLn);        \
        WAITSYNC(IT);                                                          \
        COMPUTE(BUF, BHc, BLc);                                                \
    }

    // prologue: groups 0,1 -> slots 0,1 (12 VMEM outstanding)
    STAGE(0, 0, B0h, B0l);
    STAGE(1, 1, B1h, B1l);

    for (int base = 0; base < nit; base += 4) {
        ITER(base + 0, 0, B0h, B0l, B2h, B2l);
        ITER(base + 1, 1, B1h, B1l, B3h, B3l);
        ITER(base + 2, 2, B2h, B2l, B0h, B0l);
        ITER(base + 3, 3, B3h, B3l, B1h, B1l);
    }
#undef ITER
#undef WAITSYNC
#undef COMPUTE
#undef STAGE

    // epilogue: C/D layout n = l&31, m = (r&3)+8*(r>>2)+4*(l>>5)
    int n = nt * 128 + w * 32 + lr;
    int m0 = mb * 64;
    float bv = bias ? bias[n] : 0.f;
    float* op = outp + (size_t)s * BQ * N;
    #pragma unroll
    for (int r = 0; r < 16; ++r) {
        int row = (r & 3) + 8 * (r >> 2) + 4 * lq;
        op[(size_t)(m0 + row) * N + n]      = accM0[r] + accL0[r] * (1.f / 4096.f) + bv;
        op[(size_t)(m0 + 32 + row) * N + n] = accM1[r] + accL1[r] * (1.f / 4096.f) + bv;
    }
}

// ---------------------------------------------------------------------------
// fp32 GEMM for inp = x @ w_in^T + b_in (once, K=64); writes packed cur
// ---------------------------------------------------------------------------
#define GBK 16
#define GPAD 68
__global__ __launch_bounds__(256) void gemm_in(const float* __restrict__ x,
                                               const float* __restrict__ w_in,
                                               const float* __restrict__ b_in) {
    __shared__ __align__(16) float As[GBK][GPAD];
    __shared__ __align__(16) float Bs[GBK][GPAD];
    int tid = threadIdx.x;
    int tx = tid & 15, ty = tid >> 4;
    int m0 = blockIdx.y * 64, n0 = blockIdx.x * 64;
    int lm = tid >> 2, lk = (tid & 3) << 2;
    const int K = 64;
    float acc[4][4] = {};
    for (int k0 = 0; k0 < K; k0 += GBK) {
        float4 av = *(const float4*)(x + (size_t)(m0 + lm) * K + k0 + lk);
        float4 wv = *(const float4*)(w_in + (size_t)(n0 + lm) * K + k0 + lk);
        As[lk + 0][lm] = av.x; As[lk + 1][lm] = av.y;
        As[lk + 2][lm] = av.z; As[lk + 3][lm] = av.w;
        Bs[lk + 0][lm] = wv.x; Bs[lk + 1][lm] = wv.y;
        Bs[lk + 2][lm] = wv.z; Bs[lk + 3][lm] = wv.w;
        __syncthreads();
        #pragma unroll
        for (int kk = 0; kk < GBK; ++kk) {
            float4 a  = *(const float4*)&As[kk][ty * 4];
            float4 bq = *(const float4*)&Bs[kk][tx * 4];
            float aa[4] = {a.x, a.y, a.z, a.w};
            float bb[4] = {bq.x, bq.y, bq.z, bq.w};
            #pragma unroll
            for (int i = 0; i < 4; ++i)
                #pragma unroll
                for (int j = 0; j < 4; ++j)
                    acc[i][j] = fmaf(aa[i], bb[j], acc[i][j]);
        }
        __syncthreads();
    }
    #pragma unroll
    for (int i = 0; i < 4; ++i) {
        int m = m0 + ty * 4 + i;
        int n = n0 + tx * 4;
        half4v h, lo;
        #pragma unroll
        for (int j = 0; j < 4; ++j) {
            float v = acc[i][j] + b_in[n + j];
            _Float16 hv = (_Float16)v;
            h[j] = hv;
            lo[j] = (_Float16)((v - (float)hv) * 4096.f);
        }
        size_t po = packoff(m, n, EDIM);
        *(half4v*)&g_curh[po] = h;
        *(half4v*)&g_curl[po] = lo;
    }
}

__device__ __forceinline__ float sigm(float x) { return 1.f / (1.f + expf(-x)); }

// ---------------------------------------------------------------------------
// LSTM cell 0: gates (bias fused) -> h0 (packed K=1024), c0.
// ---------------------------------------------------------------------------
__global__ void lstm0_kernel() {
    int qidx = blockIdx.x * 256 + threadIdx.x;
    int b = qidx >> 8;
    int j = (qidx & 255) * 4;
    size_t base = (size_t)b * 4096;
    float4 G[4];
    #pragma unroll
    for (int g = 0; g < 4; ++g) G[g] = *(const float4*)&g_gates[base + g * 1024 + j];
    size_t hb = (size_t)b * HDIM + j;
    float4 cin = *(const float4*)&g_c0[hb];
    float ci[4] = {cin.x, cin.y, cin.z, cin.w};
    float gi[4] = {G[0].x, G[0].y, G[0].z, G[0].w};
    float gf[4] = {G[1].x, G[1].y, G[1].z, G[1].w};
    float gg[4] = {G[2].x, G[2].y, G[2].z, G[2].w};
    float go[4] = {G[3].x, G[3].y, G[3].z, G[3].w};
    float c[4], h[4];
    half4v hh, hl;
    #pragma unroll
    for (int r = 0; r < 4; ++r) {
        c[r] = sigm(gf[r]) * ci[r] + sigm(gi[r]) * tanhf(gg[r]);
        h[r] = sigm(go[r]) * tanhf(c[r]);
        _Float16 hi16 = (_Float16)h[r];
        hh[r] = hi16;
        hl[r] = (_Float16)((h[r] - (float)hi16) * 4096.f);
    }
    *(float4*)&g_c0[hb] = {c[0], c[1], c[2], c[3]};
    size_t po = packoff(b, j, HDIM);
    *(half4v*)&g_h0h[po] = hh;
    *(half4v*)&g_h0l[po] = hl;
}

// ---------------------------------------------------------------------------
// LSTM cell 1 + LayerNorm: one block per row; writes packed h1, hn.
// ---------------------------------------------------------------------------
__global__ __launch_bounds__(256) void lstm1_ln_kernel(
    const float* __restrict__ ln_g, const float* __restrict__ ln_b)
{
    __shared__ float sbuf[4];
    int b = blockIdx.x, tid = threadIdx.x;
    int lane = tid & 63, wid = tid >> 6;
    int j = tid * 4;
    size_t base = (size_t)b * 4096;
    float4 G[4];
    #pragma unroll
    for (int g = 0; g < 4; ++g) G[g] = *(const float4*)&g_gates[base + g * 1024 + j];
    size_t hb = (size_t)b * HDIM + j;
    float4 cin = *(const float4*)&g_c1[hb];
    float ci[4] = {cin.x, cin.y, cin.z, cin.w};
    float gi[4] = {G[0].x, G[0].y, G[0].z, G[0].w};
    float gf[4] = {G[1].x, G[1].y, G[1].z, G[1].w};
    float gg[4] = {G[2].x, G[2].y, G[2].z, G[2].w};
    float go[4] = {G[3].x, G[3].y, G[3].z, G[3].w};
    float c[4], h[4];
    float sum = 0.f;
    #pragma unroll
    for (int r = 0; r < 4; ++r) {
        c[r] = sigm(gf[r]) * ci[r] + sigm(gi[r]) * tanhf(gg[r]);
        h[r] = sigm(go[r]) * tanhf(c[r]);
        sum += h[r];
    }
    *(float4*)&g_c1[hb] = {c[0], c[1], c[2], c[3]};
    size_t po = packoff(b, j, HDIM);
    half4v h1h, h1l;
    #pragma unroll
    for (int r = 0; r < 4; ++r) {
        _Float16 hi16 = (_Float16)h[r];
        h1h[r] = hi16;
        h1l[r] = (_Float16)((h[r] - (float)hi16) * 4096.f);
    }
    *(half4v*)&g_h1h[po] = h1h;
    *(half4v*)&g_h1l[po] = h1l;

    for (int off = 32; off > 0; off >>= 1) sum += __shfl_down(sum, off, 64);
    if (lane == 0) sbuf[wid] = sum;
    __syncthreads();
    float mu = (sbuf[0] + sbuf[1] + sbuf[2] + sbuf[3]) * (1.f / HDIM);
    __syncthreads();
    float sq = 0.f;
    #pragma unroll
    for (int r = 0; r < 4; ++r) { float d = h[r] - mu; sq += d * d; }
    for (int off = 32; off > 0; off >>= 1) sq += __shfl_down(sq, off, 64);
    if (lane == 0) sbuf[wid] = sq;
    __syncthreads();
    float var = (sbuf[0] + sbuf[1] + sbuf[2] + sbuf[3]) * (1.f / HDIM);
    float rstd = 1.f / sqrtf(var + 1e-5f);
    half4v nh, nl;
    #pragma unroll
    for (int r = 0; r < 4; ++r) {
        float hn = (h[r] - mu) * rstd * ln_g[j + r] + ln_b[j + r];
        _Float16 hi16 = (_Float16)hn;
        nh[r] = hi16;
        nl[r] = (_Float16)((hn - (float)hi16) * 4096.f);
    }
    *(half4v*)&g_hnh[po] = nh;
    *(half4v*)&g_hnl[po] = nl;
}

// ---------------------------------------------------------------------------
// per-row softmax over logits = sum of 4 partials + b_out; writes packed cur
// ---------------------------------------------------------------------------
__global__ __launch_bounds__(256) void softmax_row_kernel(
    const float* __restrict__ b_out, const float* __restrict__ emb,
    float* __restrict__ out, int t)
{
    __shared__ float swv[4];
    __shared__ int   swi[4];
    __shared__ float sZ[4], sS[4];
    __shared__ float s_max;
    __shared__ int   s_idx;
    int b = blockIdx.x, tid = threadIdx.x;
    int lane = tid & 63, wid = tid >> 6;
    size_t base = (size_t)b * VDIM + 4 * tid;
    float4 xv = *(const float4*)&b_out[4 * tid];
    #pragma unroll
    for (int s = 0; s < 4; ++s) {
        float4 p = *(const float4*)&g_part_lg[(size_t)s * PLS + base];
        xv.x += p.x; xv.y += p.y; xv.z += p.z; xv.w += p.w;
    }

    float mv = xv.x; int mi = 4 * tid;
    if (xv.y > mv) { mv = xv.y; mi = 4 * tid + 1; }
    if (xv.z > mv) { mv = xv.z; mi = 4 * tid + 2; }
    if (xv.w > mv) { mv = xv.w; mi = 4 * tid + 3; }
    for (int off = 32; off > 0; off >>= 1) {
        float ov = __shfl_down(mv, off, 64);
        int   oi = __shfl_down(mi, off, 64);
        if (ov > mv || (ov == mv && oi < mi)) { mv = ov; mi = oi; }
    }
    if (lane == 0) { swv[wid] = mv; swi[wid] = mi; }
    __syncthreads();
    if (tid == 0) {
        mv = swv[0]; mi = swi[0];
        for (int w = 1; w < 4; ++w)
            if (swv[w] > mv || (swv[w] == mv && swi[w] < mi)) { mv = swv[w]; mi = swi[w]; }
        s_max = mv; s_idx = mi;
    }
    __syncthreads();
    float xmax = s_max;

    float sv[4] = {xv.x - xmax, xv.y - xmax, xv.z - xmax, xv.w - xmax};
    float z = 0.f, s1 = 0.f;
    #pragma unroll
    for (int r = 0; r < 4; ++r) { float e = expf(sv[r]); z += e; s1 += e * sv[r]; }
    for (int off = 32; off > 0; off >>= 1) {
        z  += __shfl_down(z, off, 64);
        s1 += __shfl_down(s1, off, 64);
    }
    if (lane == 0) { sZ[wid] = z; sS[wid] = s1; }
    __syncthreads();
    if (tid == 0) {
        float Z = sZ[0] + sZ[1] + sZ[2] + sZ[3];
        float S1 = sS[0] + sS[1] + sS[2] + sS[3];
        float logZ = logf(Z);
        float ent = logZ - S1 / Z;
        out[(size_t)b * TOUT + t]                         = (float)s_idx;
        out[(size_t)BQ * TOUT + (size_t)b * TOUT + t]     = -logZ;
        out[(size_t)2 * BQ * TOUT + (size_t)b * TOUT + t] = ent;
    }
    __syncthreads();
    int sym = s_idx;
    const float* e = emb + (size_t)sym * EDIM;
    for (int j = tid; j < EDIM; j += 256) {
        size_t po = packoff(b, j, EDIM);
        split1(e[j], &g_curh[po], &g_curl[po]);
    }
}

// ---------------------------------------------------------------------------
extern "C" void kernel_launch(void* const* d_in, const int* in_sizes, int n_in,
                              void* d_out, int out_size, void* d_ws, size_t ws_size,
                              hipStream_t stream) {
    const float* x     = (const float*)d_in[0];
    const float* w_in  = (const float*)d_in[1];
    const float* b_in  = (const float*)d_in[2];
    const float* w_ih0 = (const float*)d_in[3];
    const float* w_hh0 = (const float*)d_in[4];
    const float* b_ih0 = (const float*)d_in[5];
    const float* b_hh0 = (const float*)d_in[6];
    const float* w_ih1 = (const float*)d_in[7];
    const float* w_hh1 = (const float*)d_in[8];
    const float* b_ih1 = (const float*)d_in[9];
    const float* b_hh1 = (const float*)d_in[10];
    const float* ln_g  = (const float*)d_in[11];
    const float* ln_b  = (const float*)d_in[12];
    const float* w_out = (const float*)d_in[13];
    const float* b_out = (const float*)d_in[14];
    const float* emb   = (const float*)d_in[15];
    float* out = (float*)d_out;

    _Float16 *wih0h, *wih0l, *whh0h, *whh0l, *wih1h, *wih1l, *whh1h, *whh1l, *wouth, *woutl;
    hipGetSymbolAddress((void**)&wih0h, HIP_SYMBOL(g_wih0h));
    hipGetSymbolAddress((void**)&wih0l, HIP_SYMBOL(g_wih0l));
    hipGetSymbolAddress((void**)&whh0h, HIP_SYMBOL(g_whh0h));
    hipGetSymbolAddress((void**)&whh0l, HIP_SYMBOL(g_whh0l));
    hipGetSymbolAddress((void**)&wih1h, HIP_SYMBOL(g_wih1h));
    hipGetSymbolAddress((void**)&wih1l, HIP_SYMBOL(g_wih1l));
    hipGetSymbolAddress((void**)&whh1h, HIP_SYMBOL(g_whh1h));
    hipGetSymbolAddress((void**)&whh1l, HIP_SYMBOL(g_whh1l));
    hipGetSymbolAddress((void**)&wouth, HIP_SYMBOL(g_wouth));
    hipGetSymbolAddress((void**)&woutl, HIP_SYMBOL(g_woutl));
    _Float16 *curh, *curl, *h0h, *h0l, *h1h, *h1l, *hnh, *hnl;
    hipGetSymbolAddress((void**)&curh, HIP_SYMBOL(g_curh));
    hipGetSymbolAddress((void**)&curl, HIP_SYMBOL(g_curl));
    hipGetSymbolAddress((void**)&h0h, HIP_SYMBOL(g_h0h));
    hipGetSymbolAddress((void**)&h0l, HIP_SYMBOL(g_h0l));
    hipGetSymbolAddress((void**)&h1h, HIP_SYMBOL(g_h1h));
    hipGetSymbolAddress((void**)&h1l, HIP_SYMBOL(g_h1l));
    hipGetSymbolAddress((void**)&hnh, HIP_SYMBOL(g_hnh));
    hipGetSymbolAddress((void**)&hnl, HIP_SYMBOL(g_hnl));
    float *gates, *part_lg, *bsum0, *bsum1;
    hipGetSymbolAddress((void**)&gates, HIP_SYMBOL(g_gates));
    hipGetSymbolAddress((void**)&part_lg, HIP_SYMBOL(g_part_lg));
    hipGetSymbolAddress((void**)&bsum0, HIP_SYMBOL(g_bsum0));
    hipGetSymbolAddress((void**)&bsum1, HIP_SYMBOL(g_bsum1));

    init_kernel<<<(BQ * HDIM) / 256, 256, 0, stream>>>(out, b_ih0, b_hh0, b_ih1, b_hh1);

    // one-time weight split+pack (klog = log2 K)
    split_pack_kernel<<<(4*HDIM*EDIM/4 + 255)/256, 256, 0, stream>>>(w_ih0, wih0h, wih0l, 9,  4*HDIM*EDIM/4);
    split_pack_kernel<<<(4*HDIM*HDIM/4 + 255)/256, 256, 0, stream>>>(w_hh0, whh0h, whh0l, 10, 4*HDIM*HDIM/4);
    split_pack_kernel<<<(4*HDIM*HDIM/4 + 255)/256, 256, 0, stream>>>(w_ih1, wih1h, wih1l, 10, 4*HDIM*HDIM/4);
    split_pack_kernel<<<(4*HDIM*HDIM/4 + 255)/256, 256, 0, stream>>>(w_hh1, whh1h, whh1l, 10, 4*HDIM*HDIM/4);
    split_pack_kernel<<<(VDIM*HDIM/4 + 255)/256, 256, 0, stream>>>(w_out, wouth, woutl, 10, VDIM*HDIM/4);

    gemm_in<<<dim3(EDIM / 64, BQ / 64), 256, 0, stream>>>(x, w_in, b_in);

    for (int t = 0; t < TLEN; ++t) {
        // gates0 = cur @ w_ih0^T + h0 @ w_hh0^T + bsum0   (S=1 direct; NT=32, NTP=4)
        gemm_pipe<<<256, 256, 0, stream>>>(
            curh, curl, EDIM, wih0h, wih0l,
            h0h, h0l, HDIM, whh0h, whh0l,
            bsum0, gates, 4 * HDIM, 1, 4);
        lstm0_kernel<<<(BQ * HDIM / 4) / 256, 256, 0, stream>>>();

        // gates1 = h0 @ w_ih1^T + h1 @ w_hh1^T + bsum1    (S=1 direct; NTP=4)
        gemm_pipe<<<256, 256, 0, stream>>>(
            h0h, h0l, HDIM, wih1h, wih1l,
            h1h, h1l, HDIM, whh1h, whh1l,
            bsum1, gates, 4 * HDIM, 1, 4);
        lstm1_ln_kernel<<<BQ, 256, 0, stream>>>(ln_g, ln_b);

        // logits partials = hn @ w_out^T   (S=4 -> 4 planes; NT=8, NTP=1)
        gemm_pipe<<<256, 256, 0, stream>>>(
            hnh, hnl, HDIM, wouth, woutl,
            (const _Float16*)nullptr, (const _Float16*)nullptr, 0,
            (const _Float16*)nullptr, (const _Float16*)nullptr,
            (const float*)nullptr, part_lg, VDIM, 4, 1);

        softmax_row_kernel<<<BQ, 256, 0, stream>>>(b_out, emb, out, t);
    }
}

// Round 9
// 2841.512 us; speedup vs baseline: 1.1380x; 1.1003x over previous
//
#include <hip/hip_runtime.h>
#include <hip/hip_bf16.h>
#include <math.h>

#define BQ   512
#define EDIM 512
#define HDIM 1024
#define VDIM 1024
#define TLEN 32
#define TOUT 33
#define PGS  (BQ * 4 * HDIM)   // gate partial plane stride
#define PLS  (BQ * VDIM)       // logits partial plane stride

typedef _Float16 half8  __attribute__((ext_vector_type(8)));
typedef _Float16 half4v __attribute__((ext_vector_type(4)));
typedef float    f32x16 __attribute__((ext_vector_type(16)));

#define GLOAD_LDS16(gp, lp) __builtin_amdgcn_global_load_lds( \
    (const __attribute__((address_space(1))) void*)(gp),      \
    (__attribute__((address_space(3))) void*)(lp), 16, 0, 0)

// Packed fragment layout for an [R][K] f16 plane (K pow2):
// (r,k) -> (r>>5)*(32K) + (k>>4)*512 + ((k>>3)&1)*256 + (r&31)*8 + (k&7)
// each (32-row strip, 16-k block) = contiguous 1KB; lane l owns row (l&31),
// k-half (l>>5) -> exactly an MFMA 32x32x16 fragment.
__device__ __forceinline__ size_t packoff(int r, int k, int K) {
    return (size_t)(r >> 5) * (size_t)(32 * K) + (size_t)(k >> 4) * 512
         + (size_t)((k >> 3) & 1) * 256 + (size_t)(r & 31) * 8 + (size_t)(k & 7);
}

// ---------------------------------------------------------------------------
// Static device buffers — write-before-read each call.
// value = hi + lo/4096 (lo pre-scaled by 2^12)
// ---------------------------------------------------------------------------
__device__ _Float16 g_curh[BQ*EDIM], g_curl[BQ*EDIM];       // packed K=512
__device__ _Float16 g_h0h[BQ*HDIM], g_h0l[BQ*HDIM];         // packed K=1024
__device__ _Float16 g_h1h[BQ*HDIM], g_h1l[BQ*HDIM];         // packed K=1024
__device__ _Float16 g_hnh[BQ*HDIM], g_hnl[BQ*HDIM];         // packed K=1024
__device__ float    g_c0[BQ*HDIM], g_c1[BQ*HDIM];

__device__ _Float16 g_wih0h[4*HDIM*EDIM], g_wih0l[4*HDIM*EDIM];  // packed K=512
__device__ _Float16 g_whh0h[4*HDIM*HDIM], g_whh0l[4*HDIM*HDIM];  // packed K=1024
__device__ _Float16 g_wih1h[4*HDIM*HDIM], g_wih1l[4*HDIM*HDIM];  // packed K=1024
__device__ _Float16 g_whh1h[4*HDIM*HDIM], g_whh1l[4*HDIM*HDIM];  // packed K=1024
__device__ _Float16 g_wouth[VDIM*HDIM],   g_woutl[VDIM*HDIM];    // packed K=1024

__device__ float g_part_g[2 * PGS];    // gate split-K partials (S=2)
__device__ float g_part_lg[8 * PLS];   // logits split-K partials (S=8)
__device__ float g_bsum0[4*HDIM], g_bsum1[4*HDIM];

// ---------------------------------------------------------------------------
__global__ void init_kernel(float* __restrict__ out,
                            const float* __restrict__ bi0, const float* __restrict__ bh0,
                            const float* __restrict__ bi1, const float* __restrict__ bh1) {
    int i = blockIdx.x * 256 + threadIdx.x;   // [0, BQ*HDIM)
    g_c0[i] = 0.f; g_c1[i] = 0.f;
    g_h0h[i] = (_Float16)0.f; g_h0l[i] = (_Float16)0.f;
    g_h1h[i] = (_Float16)0.f; g_h1l[i] = (_Float16)0.f;
    if (i < 4 * HDIM) {
        g_bsum0[i] = bi0[i] + bh0[i];
        g_bsum1[i] = bi1[i] + bh1[i];
    }
    if (i < 3 * BQ) {
        int which = i / BQ, b = i % BQ;
        out[(size_t)which * BQ * TOUT + (size_t)b * TOUT + (TOUT - 1)] = 0.f;
    }
}

// ---------------------------------------------------------------------------
// fp32 [R][K] -> packed (hi, lo*2^12) f16 planes. klog = log2(K).
// ---------------------------------------------------------------------------
__global__ void split_pack_kernel(const float* __restrict__ w, _Float16* __restrict__ hi,
                                  _Float16* __restrict__ lo, int klog, int nquads) {
    int q = blockIdx.x * 256 + threadIdx.x;
    if (q >= nquads) return;
    int e = q * 4;
    int r = e >> klog, k = e & ((1 << klog) - 1);
    float4 v = ((const float4*)w)[q];
    half4v h, l;
    h[0] = (_Float16)v.x; l[0] = (_Float16)((v.x - (float)h[0]) * 4096.f);
    h[1] = (_Float16)v.y; l[1] = (_Float16)((v.y - (float)h[1]) * 4096.f);
    h[2] = (_Float16)v.z; l[2] = (_Float16)((v.z - (float)h[2]) * 4096.f);
    h[3] = (_Float16)v.w; l[3] = (_Float16)((v.w - (float)h[3]) * 4096.f);
    size_t po = packoff(r, k, 1 << klog);
    *(half4v*)&hi[po] = h;
    *(half4v*)&lo[po] = l;
}

__device__ __forceinline__ void split1(float x, _Float16* hp, _Float16* lp) {
    _Float16 h = (_Float16)x;
    *hp = h;
    *lp = (_Float16)((x - (float)h) * 4096.f);
}

// ---------------------------------------------------------------------------
// 128x128 MFMA GEMM, 512 threads / 8 waves. Wave w = (mw = w>>2, nw = w&3)
// owns 64m x 32n (m-frags 2mw, 2mw+1). A AND B staged to LDS (fragment-linear,
// conflict-free) via global_load_lds from packed planes: 32 frags/iter,
// 4 per wave. 4-slot LDS rotation staged 2 iters ahead; counted vmcnt(8/4/0)
// + raw s_barrier (per-wave 4 VMEM/iter). Split-K over s. nit % 4 == 0.
// XCD-slab: xcd = bid&7 owns n-tiles [xcd*NTP, (xcd+1)*NTP).
// ---------------------------------------------------------------------------
__global__ __launch_bounds__(512, 2) void gemm_big(
    const _Float16* __restrict__ Ah1, const _Float16* __restrict__ Al1, int K1,
    const _Float16* __restrict__ Wh1, const _Float16* __restrict__ Wl1,
    const _Float16* __restrict__ Ah2, const _Float16* __restrict__ Al2, int K2,
    const _Float16* __restrict__ Wh2, const _Float16* __restrict__ Wl2,
    const float* __restrict__ bias, float* __restrict__ outp,
    int N, int S, int NTP)
{
    __shared__ __align__(16) _Float16 sA[4][2][4][2][512]; // [slot][pl][mf][kh] 64KB
    __shared__ __align__(16) _Float16 sB[4][2][4][2][512]; // [slot][pl][nw][kh] 64KB
    int tid = threadIdx.x;
    int l = tid & 63, w = tid >> 6;          // w in [0,8)
    int lr = l & 31, lq = l >> 5;
    int mw = w >> 2, nw = w & 3;

    int wb = blockIdx.x;
    int xcd = wb & 7, q = wb >> 3;
    int nt = xcd * NTP + q % NTP;            // n-tile (128 wide)
    int rest = q / NTP;
    int s = rest % S;
    int mb = rest / S;                        // m-tile (128 rows)

    int kch1 = K1 / S, kch2 = (K2 > 0) ? (K2 / S) : 0;
    int n1 = kch1 >> 5;
    int nit = n1 + (kch2 >> 5);

    // ---- per-wave staging assignment: frags q = w*4 + qq, qq in [0,4) ----
    const _Float16* fsrc1[4];
    const _Float16* fsrc2[4];
    _Float16* fdst0[4];
    #pragma unroll
    for (int qq = 0; qq < 4; ++qq) {
        int fq = w * 4 + qq;                 // [0,32)
        bool isA = fq < 16;
        int r_ = isA ? fq : fq - 16;
        int pl = r_ >> 3, idx = (r_ >> 1) & 3, kh = r_ & 1;
        int strip = isA ? (mb * 4 + idx) : (nt * 4 + idx);
        const _Float16* p1 = isA ? (pl ? Al1 : Ah1) : (pl ? Wl1 : Wh1);
        fsrc1[qq] = p1 + (size_t)strip * (size_t)(32 * K1)
                  + (size_t)((s * kch1) >> 4) * 512 + (size_t)kh * 512 + (size_t)l * 8;
        if (K2 > 0) {
            const _Float16* p2 = isA ? (pl ? Al2 : Ah2) : (pl ? Wl2 : Wh2);
            fsrc2[qq] = p2 + (size_t)strip * (size_t)(32 * K2)
                      + (size_t)((s * kch2) >> 4) * 512 + (size_t)kh * 512 + (size_t)l * 8;
        } else {
            fsrc2[qq] = fsrc1[qq];
        }
        fdst0[qq] = isA ? &sA[0][pl][idx][kh][0] : &sB[0][pl][idx][kh][0];
    }

    f32x16 accM0 = {}, accM1 = {}, accL0 = {}, accL1 = {};

#define STAGE(IT, SLOT)                                                        \
    {                                                                          \
        int it_ = (IT);                                                        \
        bool g1_ = it_ < n1;                                                   \
        size_t off_ = (size_t)(g1_ ? it_ : it_ - n1) * 1024;                   \
        _Pragma("unroll")                                                      \
        for (int qq = 0; qq < 4; ++qq) {                                       \
            const _Float16* sp_ = (g1_ ? fsrc1[qq] : fsrc2[qq]) + off_;        \
            GLOAD_LDS16(sp_, fdst0[qq] + (size_t)(SLOT) * 8192);               \
        }                                                                      \
    }

#define COMPUTE(BUF)                                                           \
    {                                                                          \
        _Pragma("unroll")                                                      \
        for (int kh_ = 0; kh_ < 2; ++kh_) {                                    \
            half8 ah0 = *(const half8*)&sA[BUF][0][2*mw  ][kh_][(size_t)l * 8];\
            half8 ah1 = *(const half8*)&sA[BUF][0][2*mw+1][kh_][(size_t)l * 8];\
            half8 al0 = *(const half8*)&sA[BUF][1][2*mw  ][kh_][(size_t)l * 8];\
            half8 al1 = *(const half8*)&sA[BUF][1][2*mw+1][kh_][(size_t)l * 8];\
            half8 bh  = *(const half8*)&sB[BUF][0][nw][kh_][(size_t)l * 8];    \
            half8 bl  = *(const half8*)&sB[BUF][1][nw][kh_][(size_t)l * 8];    \
            accM0 = __builtin_amdgcn_mfma_f32_32x32x16_f16(ah0, bh, accM0, 0, 0, 0); \
            accM1 = __builtin_amdgcn_mfma_f32_32x32x16_f16(ah1, bh, accM1, 0, 0, 0); \
            accL0 = __builtin_amdgcn_mfma_f32_32x32x16_f16(ah0, bl, accL0, 0, 0, 0); \
            accL1 = __builtin_amdgcn_mfma_f32_32x32x16_f16(ah1, bl, accL1, 0, 0, 0); \
            accL0 = __builtin_amdgcn_mfma_f32_32x32x16_f16(al0, bh, accL0, 0, 0, 0); \
            accL1 = __builtin_amdgcn_mfma_f32_32x32x16_f16(al1, bh, accL1, 0, 0, 0); \
        }                                                                      \
    }

// per-wave 4 VMEM/iter; 2 groups in flight => vmcnt(8) steady state
#define WAITSYNC(IT)                                                           \
    {                                                                          \
        if ((IT) < nit - 2)       asm volatile("s_waitcnt vmcnt(8)" ::: "memory"); \
        else if ((IT) == nit - 2) asm volatile("s_waitcnt vmcnt(4)" ::: "memory"); \
        else                      asm volatile("s_waitcnt vmcnt(0)" ::: "memory"); \
        __builtin_amdgcn_sched_barrier(0);                                     \
        __builtin_amdgcn_s_barrier();                                          \
    }

#define ITER(IT, BUF)                                                          \
    {                                                                          \
        if ((IT) + 2 < nit) STAGE((IT) + 2, ((BUF) + 2) & 3);                  \
        WAITSYNC(IT);                                                          \
        COMPUTE(BUF);                                                          \
    }

    STAGE(0, 0);
    STAGE(1, 1);
    for (int base = 0; base < nit; base += 4) {   // nit in {4, 24, 32}
        ITER(base + 0, 0);
        ITER(base + 1, 1);
        ITER(base + 2, 2);
        ITER(base + 3, 3);
    }
#undef ITER
#undef WAITSYNC
#undef COMPUTE
#undef STAGE

    // epilogue: C/D layout n = l&31, m = (r&3)+8*(r>>2)+4*(l>>5)
    int n = nt * 128 + nw * 32 + lr;
    int m0 = mb * 128 + mw * 64;
    float bv = bias ? bias[n] : 0.f;
    float* op = outp + (size_t)s * BQ * N;
    #pragma unroll
    for (int r = 0; r < 16; ++r) {
        int row = (r & 3) + 8 * (r >> 2) + 4 * lq;
        op[(size_t)(m0 + row) * N + n]      = accM0[r] + accL0[r] * (1.f / 4096.f) + bv;
        op[(size_t)(m0 + 32 + row) * N + n] = accM1[r] + accL1[r] * (1.f / 4096.f) + bv;
    }
}

// ---------------------------------------------------------------------------
// fp32 GEMM for inp = x @ w_in^T + b_in (once, K=64); writes packed cur
// ---------------------------------------------------------------------------
#define GBK 16
#define GPAD 68
__global__ __launch_bounds__(256) void gemm_in(const float* __restrict__ x,
                                               const float* __restrict__ w_in,
                                               const float* __restrict__ b_in) {
    __shared__ __align__(16) float As[GBK][GPAD];
    __shared__ __align__(16) float Bs[GBK][GPAD];
    int tid = threadIdx.x;
    int tx = tid & 15, ty = tid >> 4;
    int m0 = blockIdx.y * 64, n0 = blockIdx.x * 64;
    int lm = tid >> 2, lk = (tid & 3) << 2;
    const int K = 64;
    float acc[4][4] = {};
    for (int k0 = 0; k0 < K; k0 += GBK) {
        float4 av = *(const float4*)(x + (size_t)(m0 + lm) * K + k0 + lk);
        float4 wv = *(const float4*)(w_in + (size_t)(n0 + lm) * K + k0 + lk);
        As[lk + 0][lm] = av.x; As[lk + 1][lm] = av.y;
        As[lk + 2][lm] = av.z; As[lk + 3][lm] = av.w;
        Bs[lk + 0][lm] = wv.x; Bs[lk + 1][lm] = wv.y;
        Bs[lk + 2][lm] = wv.z; Bs[lk + 3][lm] = wv.w;
        __syncthreads();
        #pragma unroll
        for (int kk = 0; kk < GBK; ++kk) {
            float4 a  = *(const float4*)&As[kk][ty * 4];
            float4 bq = *(const float4*)&Bs[kk][tx * 4];
            float aa[4] = {a.x, a.y, a.z, a.w};
            float bb[4] = {bq.x, bq.y, bq.z, bq.w};
            #pragma unroll
            for (int i = 0; i < 4; ++i)
                #pragma unroll
                for (int j = 0; j < 4; ++j)
                    acc[i][j] = fmaf(aa[i], bb[j], acc[i][j]);
        }
        __syncthreads();
    }
    #pragma unroll
    for (int i = 0; i < 4; ++i) {
        int m = m0 + ty * 4 + i;
        int n = n0 + tx * 4;
        half4v h, lo;
        #pragma unroll
        for (int j = 0; j < 4; ++j) {
            float v = acc[i][j] + b_in[n + j];
            _Float16 hv = (_Float16)v;
            h[j] = hv;
            lo[j] = (_Float16)((v - (float)hv) * 4096.f);
        }
        size_t po = packoff(m, n, EDIM);
        *(half4v*)&g_curh[po] = h;
        *(half4v*)&g_curl[po] = lo;
    }
}

__device__ __forceinline__ float sigm(float x) { return 1.f / (1.f + expf(-x)); }

// ---------------------------------------------------------------------------
// LSTM cell 0: gates = part0+part1+bsum0 -> h0 (packed K=1024), c0.
// ---------------------------------------------------------------------------
__global__ void lstm0_kernel() {
    int qidx = blockIdx.x * 256 + threadIdx.x;
    int b = qidx >> 8;
    int j = (qidx & 255) * 4;
    size_t base = (size_t)b * 4096;
    float4 G[4];
    #pragma unroll
    for (int g = 0; g < 4; ++g) {
        float4 p0 = *(const float4*)&g_part_g[base + g * 1024 + j];
        float4 p1 = *(const float4*)&g_part_g[PGS + base + g * 1024 + j];
        float4 bs = *(const float4*)&g_bsum0[g * 1024 + j];
        G[g].x = p0.x + p1.x + bs.x;
        G[g].y = p0.y + p1.y + bs.y;
        G[g].z = p0.z + p1.z + bs.z;
        G[g].w = p0.w + p1.w + bs.w;
    }
    size_t hb = (size_t)b * HDIM + j;
    float4 cin = *(const float4*)&g_c0[hb];
    float ci[4] = {cin.x, cin.y, cin.z, cin.w};
    float gi[4] = {G[0].x, G[0].y, G[0].z, G[0].w};
    float gf[4] = {G[1].x, G[1].y, G[1].z, G[1].w};
    float gg[4] = {G[2].x, G[2].y, G[2].z, G[2].w};
    float go[4] = {G[3].x, G[3].y, G[3].z, G[3].w};
    float c[4], h[4];
    half4v hh, hl;
    #pragma unroll
    for (int r = 0; r < 4; ++r) {
        c[r] = sigm(gf[r]) * ci[r] + sigm(gi[r]) * tanhf(gg[r]);
        h[r] = sigm(go[r]) * tanhf(c[r]);
        _Float16 hi16 = (_Float16)h[r];
        hh[r] = hi16;
        hl[r] = (_Float16)((h[r] - (float)hi16) * 4096.f);
    }
    *(float4*)&g_c0[hb] = {c[0], c[1], c[2], c[3]};
    size_t po = packoff(b, j, HDIM);
    *(half4v*)&g_h0h[po] = hh;
    *(half4v*)&g_h0l[po] = hl;
}

// ---------------------------------------------------------------------------
// LSTM cell 1 + LayerNorm: one block per row; writes packed h1, hn.
// ---------------------------------------------------------------------------
__global__ __launch_bounds__(256) void lstm1_ln_kernel(
    const float* __restrict__ ln_g, const float* __restrict__ ln_b)
{
    __shared__ float sbuf[4];
    int b = blockIdx.x, tid = threadIdx.x;
    int lane = tid & 63, wid = tid >> 6;
    int j = tid * 4;
    size_t base = (size_t)b * 4096;
    float4 G[4];
    #pragma unroll
    for (int g = 0; g < 4; ++g) {
        float4 p0 = *(const float4*)&g_part_g[base + g * 1024 + j];
        float4 p1 = *(const float4*)&g_part_g[PGS + base + g * 1024 + j];
        float4 bs = *(const float4*)&g_bsum1[g * 1024 + j];
        G[g].x = p0.x + p1.x + bs.x;
        G[g].y = p0.y + p1.y + bs.y;
        G[g].z = p0.z + p1.z + bs.z;
        G[g].w = p0.w + p1.w + bs.w;
    }
    size_t hb = (size_t)b * HDIM + j;
    float4 cin = *(const float4*)&g_c1[hb];
    float ci[4] = {cin.x, cin.y, cin.z, cin.w};
    float gi[4] = {G[0].x, G[0].y, G[0].z, G[0].w};
    float gf[4] = {G[1].x, G[1].y, G[1].z, G[1].w};
    float gg[4] = {G[2].x, G[2].y, G[2].z, G[2].w};
    float go[4] = {G[3].x, G[3].y, G[3].z, G[3].w};
    float c[4], h[4];
    float sum = 0.f;
    #pragma unroll
    for (int r = 0; r < 4; ++r) {
        c[r] = sigm(gf[r]) * ci[r] + sigm(gi[r]) * tanhf(gg[r]);
        h[r] = sigm(go[r]) * tanhf(c[r]);
        sum += h[r];
    }
    *(float4*)&g_c1[hb] = {c[0], c[1], c[2], c[3]};
    size_t po = packoff(b, j, HDIM);
    half4v h1h, h1l;
    #pragma unroll
    for (int r = 0; r < 4; ++r) {
        _Float16 hi16 = (_Float16)h[r];
        h1h[r] = hi16;
        h1l[r] = (_Float16)((h[r] - (float)hi16) * 4096.f);
    }
    *(half4v*)&g_h1h[po] = h1h;
    *(half4v*)&g_h1l[po] = h1l;

    for (int off = 32; off > 0; off >>= 1) sum += __shfl_down(sum, off, 64);
    if (lane == 0) sbuf[wid] = sum;
    __syncthreads();
    float mu = (sbuf[0] + sbuf[1] + sbuf[2] + sbuf[3]) * (1.f / HDIM);
    __syncthreads();
    float sq = 0.f;
    #pragma unroll
    for (int r = 0; r < 4; ++r) { float d = h[r] - mu; sq += d * d; }
    for (int off = 32; off > 0; off >>= 1) sq += __shfl_down(sq, off, 64);
    if (lane == 0) sbuf[wid] = sq;
    __syncthreads();
    float var = (sbuf[0] + sbuf[1] + sbuf[2] + sbuf[3]) * (1.f / HDIM);
    float rstd = 1.f / sqrtf(var + 1e-5f);
    half4v nh, nl;
    #pragma unroll
    for (int r = 0; r < 4; ++r) {
        float hn = (h[r] - mu) * rstd * ln_g[j + r] + ln_b[j + r];
        _Float16 hi16 = (_Float16)hn;
        nh[r] = hi16;
        nl[r] = (_Float16)((hn - (float)hi16) * 4096.f);
    }
    *(half4v*)&g_hnh[po] = nh;
    *(half4v*)&g_hnl[po] = nl;
}

// ---------------------------------------------------------------------------
// per-row softmax over logits = sum of 8 partials + b_out; writes packed cur
// ---------------------------------------------------------------------------
__global__ __launch_bounds__(256) void softmax_row_kernel(
    const float* __restrict__ b_out, const float* __restrict__ emb,
    float* __restrict__ out, int t)
{
    __shared__ float swv[4];
    __shared__ int   swi[4];
    __shared__ float sZ[4], sS[4];
    __shared__ float s_max;
    __shared__ int   s_idx;
    int b = blockIdx.x, tid = threadIdx.x;
    int lane = tid & 63, wid = tid >> 6;
    size_t base = (size_t)b * VDIM + 4 * tid;
    float4 xv = *(const float4*)&b_out[4 * tid];
    #pragma unroll
    for (int s = 0; s < 8; ++s) {
        float4 p = *(const float4*)&g_part_lg[(size_t)s * PLS + base];
        xv.x += p.x; xv.y += p.y; xv.z += p.z; xv.w += p.w;
    }

    float mv = xv.x; int mi = 4 * tid;
    if (xv.y > mv) { mv = xv.y; mi = 4 * tid + 1; }
    if (xv.z > mv) { mv = xv.z; mi = 4 * tid + 2; }
    if (xv.w > mv) { mv = xv.w; mi = 4 * tid + 3; }
    for (int off = 32; off > 0; off >>= 1) {
        float ov = __shfl_down(mv, off, 64);
        int   oi = __shfl_down(mi, off, 64);
        if (ov > mv || (ov == mv && oi < mi)) { mv = ov; mi = oi; }
    }
    if (lane == 0) { swv[wid] = mv; swi[wid] = mi; }
    __syncthreads();
    if (tid == 0) {
        mv = swv[0]; mi = swi[0];
        for (int w = 1; w < 4; ++w)
            if (swv[w] > mv || (swv[w] == mv && swi[w] < mi)) { mv = swv[w]; mi = swi[w]; }
        s_max = mv; s_idx = mi;
    }
    __syncthreads();
    float xmax = s_max;

    float sv[4] = {xv.x - xmax, xv.y - xmax, xv.z - xmax, xv.w - xmax};
    float z = 0.f, s1 = 0.f;
    #pragma unroll
    for (int r = 0; r < 4; ++r) { float e = expf(sv[r]); z += e; s1 += e * sv[r]; }
    for (int off = 32; off > 0; off >>= 1) {
        z  += __shfl_down(z, off, 64);
        s1 += __shfl_down(s1, off, 64);
    }
    if (lane == 0) { sZ[wid] = z; sS[wid] = s1; }
    __syncthreads();
    if (tid == 0) {
        float Z = sZ[0] + sZ[1] + sZ[2] + sZ[3];
        float S1 = sS[0] + sS[1] + sS[2] + sS[3];
        float logZ = logf(Z);
        float ent = logZ - S1 / Z;
        out[(size_t)b * TOUT + t]                         = (float)s_idx;
        out[(size_t)BQ * TOUT + (size_t)b * TOUT + t]     = -logZ;
        out[(size_t)2 * BQ * TOUT + (size_t)b * TOUT + t] = ent;
    }
    __syncthreads();
    int sym = s_idx;
    const float* e = emb + (size_t)sym * EDIM;
    for (int j = tid; j < EDIM; j += 256) {
        size_t po = packoff(b, j, EDIM);
        split1(e[j], &g_curh[po], &g_curl[po]);
    }
}

// ---------------------------------------------------------------------------
extern "C" void kernel_launch(void* const* d_in, const int* in_sizes, int n_in,
                              void* d_out, int out_size, void* d_ws, size_t ws_size,
                              hipStream_t stream) {
    const float* x     = (const float*)d_in[0];
    const float* w_in  = (const float*)d_in[1];
    const float* b_in  = (const float*)d_in[2];
    const float* w_ih0 = (const float*)d_in[3];
    const float* w_hh0 = (const float*)d_in[4];
    const float* b_ih0 = (const float*)d_in[5];
    const float* b_hh0 = (const float*)d_in[6];
    const float* w_ih1 = (const float*)d_in[7];
    const float* w_hh1 = (const float*)d_in[8];
    const float* b_ih1 = (const float*)d_in[9];
    const float* b_hh1 = (const float*)d_in[10];
    const float* ln_g  = (const float*)d_in[11];
    const float* ln_b  = (const float*)d_in[12];
    const float* w_out = (const float*)d_in[13];
    const float* b_out = (const float*)d_in[14];
    const float* emb   = (const float*)d_in[15];
    float* out = (float*)d_out;

    _Float16 *wih0h, *wih0l, *whh0h, *whh0l, *wih1h, *wih1l, *whh1h, *whh1l, *wouth, *woutl;
    hipGetSymbolAddress((void**)&wih0h, HIP_SYMBOL(g_wih0h));
    hipGetSymbolAddress((void**)&wih0l, HIP_SYMBOL(g_wih0l));
    hipGetSymbolAddress((void**)&whh0h, HIP_SYMBOL(g_whh0h));
    hipGetSymbolAddress((void**)&whh0l, HIP_SYMBOL(g_whh0l));
    hipGetSymbolAddress((void**)&wih1h, HIP_SYMBOL(g_wih1h));
    hipGetSymbolAddress((void**)&wih1l, HIP_SYMBOL(g_wih1l));
    hipGetSymbolAddress((void**)&whh1h, HIP_SYMBOL(g_whh1h));
    hipGetSymbolAddress((void**)&whh1l, HIP_SYMBOL(g_whh1l));
    hipGetSymbolAddress((void**)&wouth, HIP_SYMBOL(g_wouth));
    hipGetSymbolAddress((void**)&woutl, HIP_SYMBOL(g_woutl));
    _Float16 *curh, *curl, *h0h, *h0l, *h1h, *h1l, *hnh, *hnl;
    hipGetSymbolAddress((void**)&curh, HIP_SYMBOL(g_curh));
    hipGetSymbolAddress((void**)&curl, HIP_SYMBOL(g_curl));
    hipGetSymbolAddress((void**)&h0h, HIP_SYMBOL(g_h0h));
    hipGetSymbolAddress((void**)&h0l, HIP_SYMBOL(g_h0l));
    hipGetSymbolAddress((void**)&h1h, HIP_SYMBOL(g_h1h));
    hipGetSymbolAddress((void**)&h1l, HIP_SYMBOL(g_h1l));
    hipGetSymbolAddress((void**)&hnh, HIP_SYMBOL(g_hnh));
    hipGetSymbolAddress((void**)&hnl, HIP_SYMBOL(g_hnl));
    float *part_g, *part_lg;
    hipGetSymbolAddress((void**)&part_g, HIP_SYMBOL(g_part_g));
    hipGetSymbolAddress((void**)&part_lg, HIP_SYMBOL(g_part_lg));

    init_kernel<<<(BQ * HDIM) / 256, 256, 0, stream>>>(out, b_ih0, b_hh0, b_ih1, b_hh1);

    // one-time weight split+pack (klog = log2 K)
    split_pack_kernel<<<(4*HDIM*EDIM/4 + 255)/256, 256, 0, stream>>>(w_ih0, wih0h, wih0l, 9,  4*HDIM*EDIM/4);
    split_pack_kernel<<<(4*HDIM*HDIM/4 + 255)/256, 256, 0, stream>>>(w_hh0, whh0h, whh0l, 10, 4*HDIM*HDIM/4);
    split_pack_kernel<<<(4*HDIM*HDIM/4 + 255)/256, 256, 0, stream>>>(w_ih1, wih1h, wih1l, 10, 4*HDIM*HDIM/4);
    split_pack_kernel<<<(4*HDIM*HDIM/4 + 255)/256, 256, 0, stream>>>(w_hh1, whh1h, whh1l, 10, 4*HDIM*HDIM/4);
    split_pack_kernel<<<(VDIM*HDIM/4 + 255)/256, 256, 0, stream>>>(w_out, wouth, woutl, 10, VDIM*HDIM/4);

    gemm_in<<<dim3(EDIM / 64, BQ / 64), 256, 0, stream>>>(x, w_in, b_in);

    for (int t = 0; t < TLEN; ++t) {
        // gates0 = cur @ w_ih0^T + h0 @ w_hh0^T   (S=2 -> part_g; nt=32, NTP=4)
        gemm_big<<<256, 512, 0, stream>>>(
            curh, curl, EDIM, wih0h, wih0l,
            h0h, h0l, HDIM, whh0h, whh0l,
            (const float*)nullptr, part_g, 4 * HDIM, 2, 4);
        lstm0_kernel<<<(BQ * HDIM / 4) / 256, 256, 0, stream>>>();

        // gates1 = h0 @ w_ih1^T + h1 @ w_hh1^T   (S=2 -> part_g; NTP=4)
        gemm_big<<<256, 512, 0, stream>>>(
            h0h, h0l, HDIM, wih1h, wih1l,
            h1h, h1l, HDIM, whh1h, whh1l,
            (const float*)nullptr, part_g, 4 * HDIM, 2, 4);
        lstm1_ln_kernel<<<BQ, 256, 0, stream>>>(ln_g, ln_b);

        // logits partials = hn @ w_out^T   (S=8 -> 8 planes; nt=8, NTP=1)
        gemm_big<<<256, 512, 0, stream>>>(
            hnh, hnl, HDIM, wouth, woutl,
            (const _Float16*)nullptr, (const _Float16*)nullptr, 0,
            (const _Float16*)nullptr, (const _Float16*)nullptr,
            (const float*)nullptr, part_lg, VDIM, 8, 1);

        softmax_row_kernel<<<BQ, 256, 0, stream>>>(b_out, emb, out, t);
    }
}